// Round 4
// baseline (1451.685 us; speedup 1.0000x reference)
//
#include <hip/hip_runtime.h>
#include <cstdint>

#define NH 12
#define DH 64
#define CC 768
#define NN 1025
#define BB 16
#define HW 32
// M = B*N = 16400 rows for both GEMMs

// ---------------- Kernel 1: CPE depthwise 3x3 + bias + residual -> pe ----------------
__global__ __launch_bounds__(192) void cpe_kernel(const float* __restrict__ in,
                                                  const float* __restrict__ w,
                                                  const float* __restrict__ bias,
                                                  float* __restrict__ pe) {
    int token = blockIdx.x;          // b*1025 + n
    int b = token / NN, n = token % NN;
    int t = threadIdx.x;             // 0..191, each handles 4 channels
    int c = t * 4;
    const float4* src4 = (const float4*)(in + (size_t)token * CC);
    float4* dst4 = (float4*)(pe + (size_t)token * CC);
    if (n == 0) { dst4[t] = src4[t]; return; }   // cls token: copy
    int p = n - 1, y = p >> 5, x = p & 31;
    float4 acc = *(const float4*)(bias + c);
    float4 ctr = src4[t];
    acc.x += ctr.x; acc.y += ctr.y; acc.z += ctr.z; acc.w += ctr.w;   // residual
    #pragma unroll
    for (int ky = 0; ky < 3; ++ky) {
        int yy = y + ky - 1;
        if (yy < 0 || yy >= HW) continue;
        #pragma unroll
        for (int kx = 0; kx < 3; ++kx) {
            int xx = x + kx - 1;
            if (xx < 0 || xx >= HW) continue;
            float4 wv = *(const float4*)(w + (size_t)(ky*3+kx)*CC + c);
            float4 iv = *(const float4*)(in + ((size_t)(b*NN) + 1 + yy*HW + xx)*CC + c);
            acc.x = fmaf(wv.x, iv.x, acc.x);
            acc.y = fmaf(wv.y, iv.y, acc.y);
            acc.z = fmaf(wv.z, iv.z, acc.z);
            acc.w = fmaf(wv.w, iv.w, acc.w);
        }
    }
    dst4[t] = acc;
}

// ---------------- fp32 tiled GEMM: C[M][Ncols] = A[M][K] @ B[K][Ncols] (+bias) --------
// 128x128 tile, BK=16, 256 threads, 8x8 per thread.
__global__ __launch_bounds__(256) void gemm128(const float* __restrict__ A,
                                               const float* __restrict__ B,
                                               const float* __restrict__ bias,
                                               float* __restrict__ C,
                                               int M, int Ncols, int K) {
    __shared__ float As[16][128];   // A^T tile
    __shared__ float Bs[16][128];
    int t = threadIdx.x;
    int row0 = blockIdx.x * 128;
    int col0 = blockIdx.y * 128;
    int arow = t & 127;
    int akg  = (t >> 7) << 3;       // 0 or 8 (k offset)
    int brow = t >> 5;              // 0..7
    int bcol = (t & 31) << 2;       // 0..124
    int ty = t >> 4, tx = t & 15;
    float acc[8][8] = {};
    for (int k0 = 0; k0 < K; k0 += 16) {
        float4 a0 = make_float4(0,0,0,0), a1 = make_float4(0,0,0,0);
        int gr = row0 + arow;
        if (gr < M) {
            const float* ap = A + (size_t)gr * K + k0 + akg;
            a0 = *(const float4*)ap;
            a1 = *(const float4*)(ap + 4);
        }
        const float* bp = B + (size_t)(k0 + brow) * Ncols + col0 + bcol;
        float4 b0 = *(const float4*)bp;
        float4 b1 = *(const float4*)(bp + (size_t)8 * Ncols);
        As[akg+0][arow] = a0.x; As[akg+1][arow] = a0.y;
        As[akg+2][arow] = a0.z; As[akg+3][arow] = a0.w;
        As[akg+4][arow] = a1.x; As[akg+5][arow] = a1.y;
        As[akg+6][arow] = a1.z; As[akg+7][arow] = a1.w;
        *(float4*)&Bs[brow][bcol]   = b0;
        *(float4*)&Bs[brow+8][bcol] = b1;
        __syncthreads();
        #pragma unroll
        for (int k = 0; k < 16; ++k) {
            float4 av0 = *(const float4*)&As[k][ty*8];
            float4 av1 = *(const float4*)&As[k][ty*8+4];
            float4 bv0 = *(const float4*)&Bs[k][tx*8];
            float4 bv1 = *(const float4*)&Bs[k][tx*8+4];
            float a[8]  = {av0.x,av0.y,av0.z,av0.w,av1.x,av1.y,av1.z,av1.w};
            float bb[8] = {bv0.x,bv0.y,bv0.z,bv0.w,bv1.x,bv1.y,bv1.z,bv1.w};
            #pragma unroll
            for (int i = 0; i < 8; ++i)
                #pragma unroll
                for (int j = 0; j < 8; ++j)
                    acc[i][j] = fmaf(a[i], bb[j], acc[i][j]);
        }
        __syncthreads();
    }
    #pragma unroll
    for (int i = 0; i < 8; ++i) {
        int row = row0 + ty*8 + i;
        if (row >= M) continue;
        #pragma unroll
        for (int j = 0; j < 8; j += 4) {
            int col = col0 + tx*8 + j;
            float4 r;
            r.x = acc[i][j+0]; r.y = acc[i][j+1];
            r.z = acc[i][j+2]; r.w = acc[i][j+3];
            if (bias) {
                r.x += bias[col]; r.y += bias[col+1];
                r.z += bias[col+2]; r.w += bias[col+3];
            }
            *(float4*)&C[(size_t)row * Ncols + col] = r;
        }
    }
}

// ---------------- Kernel 3: per-(b,h,d) max & sum(exp) of K over tokens ----------------
__global__ __launch_bounds__(256) void kstats_kernel(const float* __restrict__ qkv,
                                                     float* __restrict__ kmax,
                                                     float* __restrict__ ksum) {
    int bh = blockIdx.x;             // b*12 + h
    int b = bh / NH, h = bh % NH;
    int t = threadIdx.x;
    int d = t & 63, slice = t >> 6;  // 4 slices over tokens
    __shared__ float red[4][64];
    float m = -1e30f;
    for (int n = slice; n < NN; n += 4)
        m = fmaxf(m, qkv[(size_t)(b*NN + n)*2304 + 768 + h*64 + d]);
    red[slice][d] = m;
    __syncthreads();
    float mAll = fmaxf(fmaxf(red[0][d], red[1][d]), fmaxf(red[2][d], red[3][d]));
    __syncthreads();
    float s = 0.f;
    for (int n = slice; n < NN; n += 4)
        s += __expf(qkv[(size_t)(b*NN + n)*2304 + 768 + h*64 + d] - mAll);
    red[slice][d] = s;
    __syncthreads();
    if (slice == 0) {
        kmax[bh*64 + d] = mAll;
        ksum[bh*64 + d] = red[0][d] + red[1][d] + red[2][d] + red[3][d];
    }
}

// ---------------- Kernel 4: kTv[b,h] = softmax(K)^T @ V  (64x64 per head) -------------
__global__ __launch_bounds__(256) void ktv_kernel(const float* __restrict__ qkv,
                                                  const float* __restrict__ kmax,
                                                  const float* __restrict__ ksum,
                                                  float* __restrict__ kTv) {
    int bh = blockIdx.x;
    int b = bh / NH, h = bh % NH;
    int t = threadIdx.x;
    int d = t & 63, slice = t >> 6;
    __shared__ float sk[4][64];
    __shared__ float sv[4][64];
    __shared__ float smax[64];
    if (t < 64) smax[t] = kmax[bh*64 + t];
    __syncthreads();
    float acc[16] = {};
    int vg = slice * 16;             // this thread owns kk=d, vv=vg..vg+15
    for (int n0 = 0; n0 < NN; n0 += 4) {
        int n = n0 + slice;
        float ek = 0.f, vv = 0.f;
        if (n < NN) {
            const float* row = qkv + (size_t)(b*NN + n) * 2304;
            ek = __expf(row[768 + h*64 + d] - smax[d]);
            vv = row[1536 + h*64 + d];
        }
        sk[slice][d] = ek;
        sv[slice][d] = vv;
        __syncthreads();
        #pragma unroll
        for (int s = 0; s < 4; ++s) {
            float e = sk[s][d];
            #pragma unroll
            for (int j = 0; j < 16; ++j)
                acc[j] = fmaf(e, sv[s][vg + j], acc[j]);
        }
        __syncthreads();
    }
    float inv = 1.0f / ksum[bh*64 + d];
    #pragma unroll
    for (int j = 0; j < 16; ++j)
        kTv[(size_t)bh*4096 + (size_t)d*64 + vg + j] = acc[j] * inv;
}

// ------- Kernel 5: attn = scale*(q@kTv) + ev_hat, written in raw-reshape order --------
__global__ __launch_bounds__(256) void attn_kernel(const float* __restrict__ qkv,
                                                   const float* __restrict__ kTv,
                                                   const float* __restrict__ crpe_w,
                                                   const float* __restrict__ crpe_b,
                                                   float* __restrict__ attn) {
    int tile = blockIdx.x;
    int nt = tile % 65;              // token tile (16 tokens)
    int bh = tile / 65;
    int b = bh / NH, h = bh % NH;
    __shared__ float sKT[64][64];
    __shared__ float sq[16][68];     // padded: avoids 4-way bank conflict on sq[tt][k]
    int t = threadIdx.x;
    for (int i = t; i < 4096; i += 256)
        sKT[i >> 6][i & 63] = kTv[(size_t)bh*4096 + i];
    int tt = t >> 4;                 // token within tile
    int dd = (t & 15) << 2;          // 4 outputs per thread
    int n = nt * 16 + tt;
    float4 qv = make_float4(0,0,0,0);
    if (n < NN) qv = *(const float4*)(qkv + (size_t)(b*NN + n)*2304 + h*64 + dd);
    sq[tt][dd+0] = qv.x; sq[tt][dd+1] = qv.y;
    sq[tt][dd+2] = qv.z; sq[tt][dd+3] = qv.w;
    __syncthreads();
    float o0=0.f, o1=0.f, o2=0.f, o3=0.f;
    #pragma unroll
    for (int k = 0; k < 64; ++k) {
        float qk = sq[tt][k];
        float4 kt = *(const float4*)&sKT[k][dd];
        o0 = fmaf(qk, kt.x, o0); o1 = fmaf(qk, kt.y, o1);
        o2 = fmaf(qk, kt.z, o2); o3 = fmaf(qk, kt.w, o3);
    }
    if (n < NN) {
        float res[4] = {0.125f*o0, 0.125f*o1, 0.125f*o2, 0.125f*o3};
        if (n >= 1) {
            int np = n - 1;
            #pragma unroll
            for (int j = 0; j < 4; ++j) {
                int d = dd + j;
                int g = h*65536 + np*64 + d;     // flat index into (nh*dh, 32, 32)
                int y = g / 24576;
                int r1 = g - y*24576;
                int x = r1 / 768;
                int c = r1 - x*768;
                int hs = c >> 6;
                int c64 = c & 63;
                int ns = c64*16 + (y >> 1);
                int ds = ((y & 1) << 5) + x;
                float vsrc = qkv[(size_t)(b*NN + 1 + ns)*2304 + 1536 + hs*64 + ds];
                float conv = fmaf(vsrc, crpe_w[c], crpe_b[c]);
                res[j] = fmaf(sq[tt][d], conv, res[j]);
            }
        }
        // raw reshape (B, nh, N, dh) -> (B, N, C): flat = b*787200 + h*65600 + n*64 + d
        float4 r4 = make_float4(res[0], res[1], res[2], res[3]);
        *(float4*)&attn[(size_t)b*787200 + (size_t)h*65600 + (size_t)n*64 + dd] = r4;
    }
}

extern "C" void kernel_launch(void* const* d_in, const int* in_sizes, int n_in,
                              void* d_out, int out_size, void* d_ws, size_t ws_size,
                              hipStream_t stream) {
    const float* inputs = (const float*)d_in[0];
    const float* cpe_w  = (const float*)d_in[1];
    const float* cpe_b  = (const float*)d_in[2];
    const float* w_qkv  = (const float*)d_in[3];
    const float* crpe_w = (const float*)d_in[4];
    const float* crpe_b = (const float*)d_in[5];
    const float* w_proj = (const float*)d_in[6];
    const float* b_proj = (const float*)d_in[7];
    float* out = (float*)d_out;
    float* ws  = (float*)d_ws;

    // workspace layout (floats): pe reused as attn after qkv GEMM
    float* pe   = ws;                 // 12,595,200
    float* qkv  = ws + 12595200;      // 37,785,600
    float* kTv  = ws + 50380800;      //    786,432
    float* kmax = ws + 51167232;      //     12,288
    float* ksum = ws + 51179520;      //     12,288  -> total ~195.3 MiB

    const int M = BB * NN;            // 16400

    cpe_kernel<<<BB*NN, 192, 0, stream>>>(inputs, cpe_w, cpe_b, pe);

    dim3 g1((M + 127) / 128, 2304 / 128);
    gemm128<<<g1, 256, 0, stream>>>(pe, w_qkv, nullptr, qkv, M, 2304, 768);

    kstats_kernel<<<BB*NH, 256, 0, stream>>>(qkv, kmax, ksum);
    ktv_kernel<<<BB*NH, 256, 0, stream>>>(qkv, kmax, ksum, kTv);

    attn_kernel<<<BB*NH*65, 256, 0, stream>>>(qkv, kTv, crpe_w, crpe_b, pe /*attn*/);

    dim3 g2((M + 127) / 128, 768 / 128);
    gemm128<<<g2, 256, 0, stream>>>(pe, w_proj, b_proj, out, M, 768, 768);
}

// Round 6
// 1118.793 us; speedup vs baseline: 1.2975x; 1.2975x over previous
//
#include <hip/hip_runtime.h>
#include <cstdint>

#define NH 12
#define CC 768
#define NN 1025
#define BB 16
#define HW 32
#define MPAD 16512   // 129*128 padded rows
#define MV 16400     // valid rows (B*N)

typedef _Float16 f16;
typedef _Float16 f16x4 __attribute__((ext_vector_type(4)));
typedef _Float16 f16x8 __attribute__((ext_vector_type(8)));
typedef float    f32x4 __attribute__((ext_vector_type(4)));

__device__ __forceinline__ f16 hi_part(float x) { return (f16)x; }
__device__ __forceinline__ f16 lo_part(float x) { f16 h = (f16)x; return (f16)(x - (float)h); }

// ---------- pack A (GEMM1 input): fused CPE depthwise-3x3 + residual -> fp16 hi or lo ----------
template<int LO>
__global__ __launch_bounds__(192) void packA_cpe(const float* __restrict__ in,
                                                 const float* __restrict__ w,
                                                 const float* __restrict__ bias,
                                                 f16* __restrict__ Ah) {
    int m = blockIdx.x;              // padded row 0..16511
    int t = threadIdx.x;
    int c = t * 4;
    f16x4 o = {(f16)0, (f16)0, (f16)0, (f16)0};
    if (m < MV) {
        int b = m / NN, n = m % NN;
        float4 acc;
        if (n == 0) {
            acc = *(const float4*)(in + (size_t)m * CC + c);   // cls token: copy
        } else {
            int p = n - 1, y = p >> 5, x = p & 31;
            acc = *(const float4*)(bias + c);
            float4 ctr = *(const float4*)(in + (size_t)m * CC + c);
            acc.x += ctr.x; acc.y += ctr.y; acc.z += ctr.z; acc.w += ctr.w;  // residual
            #pragma unroll
            for (int ky = 0; ky < 3; ++ky) {
                int yy = y + ky - 1;
                if (yy < 0 || yy >= HW) continue;
                #pragma unroll
                for (int kx = 0; kx < 3; ++kx) {
                    int xx = x + kx - 1;
                    if (xx < 0 || xx >= HW) continue;
                    float4 wv = *(const float4*)(w + (size_t)(ky*3+kx)*CC + c);
                    float4 iv = *(const float4*)(in + ((size_t)(b*NN) + 1 + yy*HW + xx)*CC + c);
                    acc.x = fmaf(wv.x, iv.x, acc.x);
                    acc.y = fmaf(wv.y, iv.y, acc.y);
                    acc.z = fmaf(wv.z, iv.z, acc.z);
                    acc.w = fmaf(wv.w, iv.w, acc.w);
                }
            }
        }
        if (LO) { o[0]=lo_part(acc.x); o[1]=lo_part(acc.y); o[2]=lo_part(acc.z); o[3]=lo_part(acc.w); }
        else    { o[0]=hi_part(acc.x); o[1]=hi_part(acc.y); o[2]=hi_part(acc.z); o[3]=hi_part(acc.w); }
    }
    *(f16x4*)&Ah[(size_t)m * CC + c] = o;
}

// ---------- pack A (GEMM2 input): attention output lives in qkv k-columns ----------
template<int LO>
__global__ __launch_bounds__(192) void packA_attn(const float* __restrict__ qkv,
                                                  f16* __restrict__ Ah) {
    int m = blockIdx.x;
    int t = threadIdx.x;
    int c = t * 4;
    f16x4 o = {(f16)0, (f16)0, (f16)0, (f16)0};
    if (m < MV) {
        float4 v = *(const float4*)&qkv[(size_t)m * 2304 + 768 + c];
        if (LO) { o[0]=lo_part(v.x); o[1]=lo_part(v.y); o[2]=lo_part(v.z); o[3]=lo_part(v.w); }
        else    { o[0]=hi_part(v.x); o[1]=hi_part(v.y); o[2]=hi_part(v.z); o[3]=hi_part(v.w); }
    }
    *(f16x4*)&Ah[(size_t)m * CC + c] = o;
}

// ---------- pack B^T: W[768][Nc] fp32 -> Bt[Nc][1536] fp16, [n][0:768]=hi, [n][768:1536]=lo ----------
__global__ __launch_bounds__(256) void packBT(const float* __restrict__ W,
                                              f16* __restrict__ Bt, int Nc) {
    __shared__ float tile[32][33];
    int k0 = blockIdx.x * 32, n0 = blockIdx.y * 32;
    int t = threadIdx.x;
    int ty = t >> 3, tx4 = (t & 7) << 2;
    float4 v = *(const float4*)&W[(size_t)(k0 + ty) * Nc + n0 + tx4];
    tile[ty][tx4+0] = v.x; tile[ty][tx4+1] = v.y; tile[ty][tx4+2] = v.z; tile[ty][tx4+3] = v.w;
    __syncthreads();
    int nl = ty, kl = tx4;
    f16x4 oh, ol;
    #pragma unroll
    for (int i = 0; i < 4; ++i) {
        float x = tile[kl + i][nl];
        f16 h = (f16)x;
        oh[i] = h;
        ol[i] = (f16)(x - (float)h);
    }
    size_t base = (size_t)(n0 + nl) * 1536 + (k0 + kl);
    *(f16x4*)&Bt[base]       = oh;
    *(f16x4*)&Bt[base + 768] = ol;
}

// ---------- MFMA GEMM: C[MV][Nc] (=|+=) A[MPAD][768] x Bt-sections, 128x128 tile ----------
// step s: k-slice kk=(s%24)*32 of A; B column-offset 0 for s<24 else boff1 (hi|lo sections).
template<int ACC>
__global__ __launch_bounds__(256) void gemm_mfma(const f16* __restrict__ A,
                                                 const f16* __restrict__ Bt,
                                                 const float* __restrict__ bias,
                                                 float* __restrict__ C,
                                                 int Nc, int nsteps, int boff1) {
    __shared__ f16 As[128][32];
    __shared__ f16 Bs[128][32];
    int t = threadIdx.x;
    int w = t >> 6, l = t & 63;
    int row0 = blockIdx.x * 128, col0 = blockIdx.y * 128;
    int wm = w >> 1, wn = w & 1;              // 2x2 wave grid, 64x64 each
    int r0 = t >> 2, kc0 = (t & 3) << 3;      // staging chunk 0 (rows 0..63)
    int r1 = 64 + r0;                         // staging chunk 1 (rows 64..127)
    f32x4 zz = {0.f, 0.f, 0.f, 0.f};
    f32x4 acc[4][4];
    #pragma unroll
    for (int i = 0; i < 4; ++i)
        #pragma unroll
        for (int j = 0; j < 4; ++j) acc[i][j] = zz;

    for (int s = 0; s < nsteps; ++s) {
        int kk = (s % 24) * 32;
        int bo = (s < 24 ? 0 : boff1) + kk;
        const f16* Ag = A  + (size_t)row0 * 768  + kk;
        const f16* Bg = Bt + (size_t)col0 * 1536 + bo;
        f16x8 a0 = *(const f16x8*)(Ag + (size_t)r0 * 768  + kc0);
        f16x8 a1 = *(const f16x8*)(Ag + (size_t)r1 * 768  + kc0);
        f16x8 b0 = *(const f16x8*)(Bg + (size_t)r0 * 1536 + kc0);
        f16x8 b1 = *(const f16x8*)(Bg + (size_t)r1 * 1536 + kc0);
        __syncthreads();                       // prev iteration's LDS reads done
        *(f16x8*)&As[r0][kc0] = a0;
        *(f16x8*)&As[r1][kc0] = a1;
        *(f16x8*)&Bs[r0][kc0] = b0;
        *(f16x8*)&Bs[r1][kc0] = b1;
        __syncthreads();
        f16x8 af[4], bf[4];
        #pragma unroll
        for (int i = 0; i < 4; ++i)
            af[i] = *(const f16x8*)&As[wm*64 + i*16 + (l & 15)][(l >> 4) * 8];
        #pragma unroll
        for (int j = 0; j < 4; ++j)
            bf[j] = *(const f16x8*)&Bs[wn*64 + j*16 + (l & 15)][(l >> 4) * 8];
        #pragma unroll
        for (int i = 0; i < 4; ++i)
            #pragma unroll
            for (int j = 0; j < 4; ++j)
                acc[i][j] = __builtin_amdgcn_mfma_f32_16x16x32_f16(af[i], bf[j], acc[i][j], 0, 0, 0);
    }
    // epilogue: D lane map col=l&15, row=(l>>4)*4+r  [m89/m91-verified]
    #pragma unroll
    for (int i = 0; i < 4; ++i) {
        #pragma unroll
        for (int j = 0; j < 4; ++j) {
            int gc = col0 + wn*64 + j*16 + (l & 15);
            #pragma unroll
            for (int r = 0; r < 4; ++r) {
                int gr = row0 + wm*64 + i*16 + (l >> 4) * 4 + r;
                if (gr < MV) {
                    size_t off = (size_t)gr * Nc + gc;
                    float v = acc[i][j][r];
                    if (ACC) C[off] += v;
                    else     C[off] = bias ? v + bias[gc] : v;
                }
            }
        }
    }
}

// ---------- per-(b,h,d) max & sum(exp) of K over tokens ----------
__global__ __launch_bounds__(256) void kstats_kernel(const float* __restrict__ qkv,
                                                     float* __restrict__ kmax,
                                                     float* __restrict__ ksum) {
    int bh = blockIdx.x;
    int b = bh / NH, h = bh % NH;
    int t = threadIdx.x;
    int d = t & 63, slice = t >> 6;
    __shared__ float red[4][64];
    float m = -1e30f;
    for (int n = slice; n < NN; n += 4)
        m = fmaxf(m, qkv[(size_t)(b*NN + n)*2304 + 768 + h*64 + d]);
    red[slice][d] = m;
    __syncthreads();
    float mAll = fmaxf(fmaxf(red[0][d], red[1][d]), fmaxf(red[2][d], red[3][d]));
    __syncthreads();
    float s = 0.f;
    for (int n = slice; n < NN; n += 4)
        s += __expf(qkv[(size_t)(b*NN + n)*2304 + 768 + h*64 + d] - mAll);
    red[slice][d] = s;
    __syncthreads();
    if (slice == 0) {
        kmax[bh*64 + d] = mAll;
        ksum[bh*64 + d] = red[0][d] + red[1][d] + red[2][d] + red[3][d];
    }
}

// ---------- kTv[b,h] = softmax(K)^T @ V ----------
__global__ __launch_bounds__(256) void ktv_kernel(const float* __restrict__ qkv,
                                                  const float* __restrict__ kmax,
                                                  const float* __restrict__ ksum,
                                                  float* __restrict__ kTv) {
    int bh = blockIdx.x;
    int b = bh / NH, h = bh % NH;
    int t = threadIdx.x;
    int d = t & 63, slice = t >> 6;
    __shared__ float sk[4][64];
    __shared__ float sv[4][64];
    __shared__ float smax[64];
    if (t < 64) smax[t] = kmax[bh*64 + t];
    __syncthreads();
    float acc[16] = {};
    int vg = slice * 16;
    for (int n0 = 0; n0 < NN; n0 += 4) {
        int n = n0 + slice;
        float ek = 0.f, vv = 0.f;
        if (n < NN) {
            const float* row = qkv + (size_t)(b*NN + n) * 2304;
            ek = __expf(row[768 + h*64 + d] - smax[d]);
            vv = row[1536 + h*64 + d];
        }
        sk[slice][d] = ek;
        sv[slice][d] = vv;
        __syncthreads();
        #pragma unroll
        for (int s = 0; s < 4; ++s) {
            float e = sk[s][d];
            #pragma unroll
            for (int j = 0; j < 16; ++j)
                acc[j] = fmaf(e, sv[s][vg + j], acc[j]);
        }
        __syncthreads();
    }
    float inv = 1.0f / ksum[bh*64 + d];
    #pragma unroll
    for (int j = 0; j < 16; ++j)
        kTv[(size_t)bh*4096 + (size_t)d*64 + vg + j] = acc[j] * inv;
}

// ---------- attn = scale*(q@kTv) + ev_hat, written into qkv's dead K-columns ----------
__global__ __launch_bounds__(256) void attn_kernel(float* qkv,
                                                   const float* __restrict__ kTv,
                                                   const float* __restrict__ crpe_w,
                                                   const float* __restrict__ crpe_b) {
    int tile = blockIdx.x;
    int nt = tile % 65;
    int bh = tile / 65;
    int b = bh / NH, h = bh % NH;
    __shared__ float sKT[64][64];
    __shared__ float sq[16][68];
    int t = threadIdx.x;
    for (int i = t; i < 4096; i += 256)
        sKT[i >> 6][i & 63] = kTv[(size_t)bh*4096 + i];
    int tt = t >> 4;
    int dd = (t & 15) << 2;
    int n = nt * 16 + tt;
    float4 qv = make_float4(0,0,0,0);
    if (n < NN) qv = *(const float4*)(qkv + (size_t)(b*NN + n)*2304 + h*64 + dd);
    sq[tt][dd+0] = qv.x; sq[tt][dd+1] = qv.y;
    sq[tt][dd+2] = qv.z; sq[tt][dd+3] = qv.w;
    __syncthreads();
    float o0=0.f, o1=0.f, o2=0.f, o3=0.f;
    #pragma unroll
    for (int k = 0; k < 64; ++k) {
        float qk = sq[tt][k];
        float4 kt = *(const float4*)&sKT[k][dd];
        o0 = fmaf(qk, kt.x, o0); o1 = fmaf(qk, kt.y, o1);
        o2 = fmaf(qk, kt.z, o2); o3 = fmaf(qk, kt.w, o3);
    }
    if (n < NN) {
        float res[4] = {0.125f*o0, 0.125f*o1, 0.125f*o2, 0.125f*o3};
        if (n >= 1) {
            int np = n - 1;
            #pragma unroll
            for (int j = 0; j < 4; ++j) {
                int d = dd + j;
                int g = h*65536 + np*64 + d;
                int y = g / 24576;
                int r1 = g - y*24576;
                int x = r1 / 768;
                int c = r1 - x*768;
                int hs = c >> 6;
                int c64 = c & 63;
                int ns = c64*16 + (y >> 1);
                int ds = ((y & 1) << 5) + x;
                float vsrc = qkv[(size_t)(b*NN + 1 + ns)*2304 + 1536 + hs*64 + ds];
                float conv = fmaf(vsrc, crpe_w[c], crpe_b[c]);
                res[j] = fmaf(sq[tt][d], conv, res[j]);
            }
        }
        // flat (B,nh,N,dh) index, remapped into qkv K-columns: row=f/768, col=768+f%768
        size_t f = (size_t)b*787200 + (size_t)h*65600 + (size_t)n*64 + dd;
        size_t adr = (f / 768) * 2304 + 768 + (f % 768);
        float4 r4 = make_float4(res[0], res[1], res[2], res[3]);
        *(float4*)&qkv[adr] = r4;
    }
}

extern "C" void kernel_launch(void* const* d_in, const int* in_sizes, int n_in,
                              void* d_out, int out_size, void* d_ws, size_t ws_size,
                              hipStream_t stream) {
    const float* inputs = (const float*)d_in[0];
    const float* cpe_w  = (const float*)d_in[1];
    const float* cpe_b  = (const float*)d_in[2];
    const float* w_qkv  = (const float*)d_in[3];
    const float* crpe_w = (const float*)d_in[4];
    const float* crpe_b = (const float*)d_in[5];
    const float* w_proj = (const float*)d_in[6];
    const float* b_proj = (const float*)d_in[7];
    float* out = (float*)d_out;
    float* ws  = (float*)d_ws;

    // ws layout (floats), total 45,895,680 f = 183.6 MB (< 204.8 MB proven-safe):
    f16*   Ah   = (f16*)ws;               // 16512*768 halves = 6,340,608 f
    float* qkv  = ws + 6340608;           // 16400*2304        = 37,785,600 f (K-cols reused for attn out)
    float* aux  = ws + 44126208;          // 1,769,472 f region:
    f16*   BpT1 = (f16*)aux;              //   GEMM1: 2304*1536 halves
    float* kTv  = aux;                    //   after GEMM1: 786,432 f
    float* kmax = aux + 786432;           //   12,288 f
    float* ksum = aux + 798720;           //   12,288 f
    f16*   BpT2 = (f16*)(aux + 811008);   //   768*1536 halves = 589,824 f

    // ---- GEMM1: qkv = pe @ w_qkv  (fp16 split: AhiBhi + AhiBlo, then += AloBhi) ----
    packBT<<<dim3(24, 72), 256, 0, stream>>>(w_qkv, BpT1, 2304);
    packA_cpe<0><<<MPAD, 192, 0, stream>>>(inputs, cpe_w, cpe_b, Ah);
    gemm_mfma<0><<<dim3(129, 18), 256, 0, stream>>>(Ah, BpT1, nullptr, qkv, 2304, 48, 768);
    packA_cpe<1><<<MPAD, 192, 0, stream>>>(inputs, cpe_w, cpe_b, Ah);
    gemm_mfma<1><<<dim3(129, 18), 256, 0, stream>>>(Ah, BpT1, nullptr, qkv, 2304, 24, 0);

    // ---- factorized attention ----
    kstats_kernel<<<BB*NH, 256, 0, stream>>>(qkv, kmax, ksum);
    ktv_kernel<<<BB*NH, 256, 0, stream>>>(qkv, kmax, ksum, kTv);
    attn_kernel<<<BB*NH*65, 256, 0, stream>>>(qkv, kTv, crpe_w, crpe_b);

    // ---- GEMM2: out = attn @ w_proj + b_proj ----
    packBT<<<dim3(24, 24), 256, 0, stream>>>(w_proj, BpT2, 768);
    packA_attn<0><<<MPAD, 192, 0, stream>>>(qkv, Ah);
    gemm_mfma<0><<<dim3(129, 6), 256, 0, stream>>>(Ah, BpT2, b_proj, out, 768, 48, 768);
    packA_attn<1><<<MPAD, 192, 0, stream>>>(qkv, Ah);
    gemm_mfma<1><<<dim3(129, 6), 256, 0, stream>>>(Ah, BpT2, nullptr, out, 768, 24, 0);
}